// Round 8
// baseline (102.068 us; speedup 1.0000x reference)
//
#include <hip/hip_runtime.h>
#include <math.h>

#define B 512
#define N 256
#define E 1024
#define D 256
#define H 256
#define C 8
#define U 64

// ---------------------------------------------------------------------------
// Mask dtype sniffing: flag 0 = int32 words, 1 = byte-packed bool, 2 = float32
// ---------------------------------------------------------------------------
__device__ __forceinline__ float mask_val(const void* m, long i, int flag) {
    if (flag == 1) return ((const unsigned char*)m)[i] ? 1.f : 0.f;
    if (flag == 2) return (((const float*)m)[i] != 0.f) ? 1.f : 0.f;
    return ((const int*)m)[i] ? 1.f : 0.f;
}

// block-wide sum reduction (256 threads)
__device__ __forceinline__ float block_sum(float v, float* red) {
    int t = threadIdx.x;
    red[t] = v; __syncthreads();
    for (int s = 128; s > 0; s >>= 1) {
        if (t < s) red[t] += red[t + s];
        __syncthreads();
    }
    float r = red[0]; __syncthreads();
    return r;
}

// ---------------------------------------------------------------------------
// k_h: per-batch trunk, 2 rows/block, 512 threads, grid=256.
// Block 0 sniffs the mask dtype into *flag.
// ---------------------------------------------------------------------------
__global__ __launch_bounds__(512) void k_h(
    const float* __restrict__ feat,
    const float* __restrict__ Wc1, const float* __restrict__ bc1,
    const float* __restrict__ Wc2, const float* __restrict__ bc2,
    const float* __restrict__ Wn1, const float* __restrict__ bn1,
    const float* __restrict__ We1, const float* __restrict__ be1,
    const float* __restrict__ Wg,  const float* __restrict__ bg,
    const float* __restrict__ margin, const float* __restrict__ brisk,
    const unsigned int* __restrict__ amask_words,
    float* __restrict__ base_n, float* __restrict__ base_e,
    float* __restrict__ out_gate, int* __restrict__ flag)
{
    __shared__ __align__(16) float sF[2][256];
    __shared__ __align__(16) float sH[2][256];
    __shared__ float red[512];
    __shared__ int cls0, cls1;

    int t = threadIdx.x;
    int w = t >> 8;        // 0/1: row in P1/P2, matrix in P3
    int c = t & 255;
    int b0 = blockIdx.x * 2;
    int b = b0 + w;

    if (blockIdx.x == 0) {
        if (t == 0) { cls0 = 0; cls1 = 0; }
        __syncthreads();
        if (t < 256) {
            unsigned int wd = amask_words[t];
            if (wd != 0u && wd != 1u) {
                if (wd == 0x3f800000u) atomicOr(&cls1, 1);
                else                   atomicOr(&cls0, 1);
            }
        }
        __syncthreads();
        if (t == 0) *flag = cls0 ? 1 : (cls1 ? 2 : 0);
    }

    sF[w][c] = feat[(long)b * D + c];
    __syncthreads();

    // ---- P1: relu(feat @ Wc1 + bc1) -> sH ----
    {
        float acc[4] = {bc1[c], 0.f, 0.f, 0.f};
        const float* Wp = Wc1 + c;
        for (int d0 = 0; d0 < D; d0 += 16) {
            float wv[16];
            #pragma unroll
            for (int k = 0; k < 16; k++) wv[k] = Wp[(long)(d0 + k) * H];
            #pragma unroll
            for (int k = 0; k < 16; k++)
                acc[k & 3] = fmaf(sF[w][d0 + k], wv[k], acc[k & 3]);
        }
        sH[w][c] = fmaxf((acc[0] + acc[1]) + (acc[2] + acc[3]), 0.f);
    }
    __syncthreads();

    // ---- P2: h = relu(A @ Wc2 + bc2) -> sF ----
    {
        float acc[4] = {bc2[c], 0.f, 0.f, 0.f};
        const float* Wp = Wc2 + c;
        for (int d0 = 0; d0 < H; d0 += 16) {
            float wv[16];
            #pragma unroll
            for (int k = 0; k < 16; k++) wv[k] = Wp[(long)(d0 + k) * H];
            #pragma unroll
            for (int k = 0; k < 16; k++)
                acc[k & 3] = fmaf(sH[w][d0 + k], wv[k], acc[k & 3]);
        }
        float a = fmaxf((acc[0] + acc[1]) + (acc[2] + acc[3]), 0.f);
        __syncthreads();
        sF[w][c] = a;                 // sF now holds h for both rows
    }
    __syncthreads();

    // ---- gate per row ----
    red[t] = sF[w][c] * Wg[c];
    __syncthreads();
    for (int s = 128; s > 0; s >>= 1) {
        if (c < s) red[t] += red[t + s];
        __syncthreads();
    }
    if (c == 0) {
        float lg = 1.f / (1.f + expf(-(red[t] + bg[0])));
        out_gate[b] = ((margin[b] < 0.2f) || (brisk[b] > 0.6f) || (lg > 0.5f)) ? 1.f : 0.f;
    }

    // ---- P3: base_n / base_e (thread-half = matrix, both rows) ----
    {
        const float* W3  = w ? (We1 + c) : (Wn1 + c);
        float bias       = w ? be1[c]    : bn1[c];
        float* dst       = w ? base_e    : base_n;
        float aA[2] = {bias, 0.f};
        float aB[2] = {bias, 0.f};
        for (int d0 = 0; d0 < H; d0 += 16) {
            float wv[16];
            #pragma unroll
            for (int k = 0; k < 16; k++) wv[k] = W3[(long)(d0 + k) * H];
            #pragma unroll
            for (int k = 0; k < 16; k++) {
                aA[k & 1] = fmaf(sF[0][d0 + k], wv[k], aA[k & 1]);
                aB[k & 1] = fmaf(sF[1][d0 + k], wv[k], aB[k & 1]);
            }
        }
        dst[(long)b0 * H + c]       = aA[0] + aA[1];
        dst[(long)(b0 + 1) * H + c] = aB[0] + aB[1];
    }
}

// ---------------------------------------------------------------------------
// k_ne: 128 threads = 2 waves per block.
// Blocks [0,256): NODE, 2 rows/block (wave = full row, 4 items/lane, full
//   256-j loop, pack shared across both waves). Finalization = pure shuffle
//   reductions in-wave (centering, top-2+idx, margin, riskbase).
// Blocks [256,768): EDGE, 1 row/block (wave = half row, 8 items/lane).
// Pack [256][12] in LDS -> 3 uniform ds_read_b128 per j per wave.
// ---------------------------------------------------------------------------
__global__ __launch_bounds__(128) void k_ne(
    const float* __restrict__ cs, const float* __restrict__ coords,
    const float* __restrict__ unc, const int* __restrict__ actions,
    const void* __restrict__ amask,
    const float* __restrict__ Wn1, const float* __restrict__ Wn2,
    const float* __restrict__ bn2, const float* __restrict__ base_n,
    const float* __restrict__ es, const int* __restrict__ edges,
    const void* __restrict__ emask,
    const float* __restrict__ We1, const float* __restrict__ We2,
    const float* __restrict__ be2, const float* __restrict__ base_e,
    const float* __restrict__ gate, const int* __restrict__ flagp,
    float* __restrict__ out0, float* __restrict__ out1,
    float* __restrict__ out2, float* __restrict__ out3,
    float* __restrict__ riskbase)
{
    __shared__ __align__(16) float smem[3072 + 2304]; // pack + (sB | sC)
    float* pack = smem;
    int t = threadIdx.x;
    int w = t >> 6, lane = t & 63;
    int flag = *flagp;

    if (blockIdx.x < 256) {
        // ================= NODE: 2 rows, wave = row =================
        int b0 = blockIdx.x * 2;
        float* sB = smem + 3072;   // [2][256] bases

        // stage pack (thread t handles j = t, t+128) + bases
        #pragma unroll
        for (int s = 0; s < 2; s++) {
            int j = t + 128 * s;
            float* p = pack + j * 12;
            #pragma unroll
            for (int k = 0; k < 10; k++) p[k] = Wn1[(long)(H + k) * H + j];
            p[10] = Wn2[j];
            p[11] = 0.f;
            sB[j]       = base_n[(long)b0 * H + j];
            sB[256 + j] = base_n[(long)(b0 + 1) * H + j];
        }
        __syncthreads();

        int b = b0 + w;
        float g = gate[b];
        float b2v = bn2[0];

        // load items: n = q*64 + lane
        float f8v[4], ug[4], amv[4], acc[4];
        float f0[4], f1[4], f2[4], f3[4], f4[4], f5[4], f6[4], f7[4];
        #pragma unroll
        for (int q = 0; q < 4; q++) {
            int n = q * 64 + lane;
            const float4* cp = (const float4*)(coords + ((long)b * N + n) * C);
            float4 c0 = cp[0], c1 = cp[1];
            f0[q] = c0.x; f1[q] = c0.y; f2[q] = c0.z; f3[q] = c0.w;
            f4[q] = c1.x; f5[q] = c1.y; f6[q] = c1.z; f7[q] = c1.w;
            f8v[q] = cs[(long)b * N + n];
            int a = actions[(long)b * N + n];
            a = min(max(a, 0), U - 1);
            ug[q] = unc[(long)b * U + a];
            amv[q] = mask_val(amask, (long)b * N + n, flag);
            acc[q] = b2v;
        }

        float raw[4];
        if (g != 0.f) {
            const float* sBw = sB + w * 256;
            #pragma unroll 2
            for (int j = 0; j < H; j++) {
                const float* pj = pack + j * 12;
                float4 wa = *(const float4*)(pj);
                float4 wb = *(const float4*)(pj + 4);
                float4 wc = *(const float4*)(pj + 8);
                float bse = sBw[j];
                #pragma unroll
                for (int q = 0; q < 4; q++) {
                    float zA = fmaf(f0[q], wa.x, bse);
                    zA = fmaf(f1[q], wa.y, zA);
                    zA = fmaf(f2[q], wa.z, zA);
                    zA = fmaf(f3[q], wa.w, zA);
                    float zB = f4[q] * wb.x;
                    zB = fmaf(f5[q], wb.y, zB);
                    zB = fmaf(f6[q], wb.z, zB);
                    zB = fmaf(f7[q], wb.w, zB);
                    zB = fmaf(f8v[q], wc.x, zB);
                    zB = fmaf(ug[q], wc.y, zB);
                    acc[q] = fmaf(fmaxf(zA + zB, 0.f), wc.z, acc[q]);
                }
            }
            #pragma unroll
            for (int q = 0; q < 4; q++)
                raw[q] = (f8v[q] + g * 0.1f * (acc[q] * amv[q])) * amv[q];
        } else {
            #pragma unroll
            for (int q = 0; q < 4; q++) raw[q] = f8v[q] * amv[q];
        }

        // ---- wave-level finalization (no barriers) ----
        float s = 0.f, cn = 0.f, su = 0.f;
        #pragma unroll
        for (int q = 0; q < 4; q++) {
            s += raw[q]; cn += amv[q]; su += ug[q] * amv[q];
        }
        #pragma unroll
        for (int m = 1; m < 64; m <<= 1) {
            s  += __shfl_xor(s, m);
            cn += __shfl_xor(cn, m);
            su += __shfl_xor(su, m);
        }
        float denom = fmaxf(cn, 1.f);
        float mu = s / denom;

        float rs[4], masked[4];
        #pragma unroll
        for (int q = 0; q < 4; q++) {
            rs[q] = (raw[q] - mu) * amv[q];
            out0[(long)b * N + q * 64 + lane] = rs[q];
            masked[q] = (amv[q] != 0.f) ? rs[q] : -1e9f;
        }

        // local top-2 (indices ascend with q, ties keep lower idx)
        float v1 = masked[0]; int i1 = lane; float v2 = -1e9f;
        #pragma unroll
        for (int q = 1; q < 4; q++) {
            float mv = masked[q]; int mi = q * 64 + lane;
            if (mv > v1) { v2 = v1; v1 = mv; i1 = mi; }
            else v2 = fmaxf(v2, mv);
        }
        // butterfly top-2 merge
        #pragma unroll
        for (int m = 1; m < 64; m <<= 1) {
            float ov1 = __shfl_xor(v1, m);
            int   oi1 = __shfl_xor(i1, m);
            float ov2 = __shfl_xor(v2, m);
            bool ow = (ov1 > v1) || (ov1 == v1 && oi1 < i1);
            float lv  = ow ? v1 : ov1;
            float wv2 = ow ? ov2 : v2;
            if (ow) { v1 = ov1; i1 = oi1; }
            v2 = fmaxf(lv, wv2);
        }

        if (lane == 0) {
            float rmargin = v1 - v2;
            out1[b] = rmargin;
            out3[b] = (float)i1;
            float sig = 1.f / (1.f + expf(rmargin));   // sigmoid(-margin)
            riskbase[b] = sig + 0.1f * (su / denom);
        }
    } else {
        // ================= EDGE: 1 row, wave = half row =================
        int b = blockIdx.x - 256;
        float g = gate[b];

        if (g == 0.f) {
            #pragma unroll
            for (int q = 0; q < 8; q++) {
                long idx = (long)b * E + t + 128 * q;
                float em = mask_val(emask, idx, flag);
                out2[idx] = es[idx] * em;
            }
            return;
        }

        float* sC = smem + 3072;   // [256][9] padded coords

        // stage coords: thread t stages nodes 2t, 2t+1 (stride-9 layout)
        {
            const float4* g4 = (const float4*)(coords + (long)b * N * C);
            float4 c0 = g4[4 * t + 0], c1 = g4[4 * t + 1];
            float4 c2 = g4[4 * t + 2], c3 = g4[4 * t + 3];
            float* d0 = sC + (2 * t) * 9;
            d0[0] = c0.x; d0[1] = c0.y; d0[2] = c0.z; d0[3] = c0.w;
            d0[4] = c1.x; d0[5] = c1.y; d0[6] = c1.z; d0[7] = c1.w;
            float* d1 = sC + (2 * t + 1) * 9;
            d1[0] = c2.x; d1[1] = c2.y; d1[2] = c2.z; d1[3] = c2.w;
            d1[4] = c3.x; d1[5] = c3.y; d1[6] = c3.z; d1[7] = c3.w;
        }
        // stage pack: [j][0..7]=We1 k<8, [8]=We1 k=8 (es w), [9]=We2,
        // [10]=base_e[b]+w9 (emf fold), [11]=pad
        #pragma unroll
        for (int sdx = 0; sdx < 2; sdx++) {
            int j = t + 128 * sdx;
            float* p = pack + j * 12;
            #pragma unroll
            for (int k = 0; k < 9; k++) p[k] = We1[(long)(H + k) * H + j];
            p[9] = We2[j];
            p[10] = base_e[(long)b * H + j] + We1[(long)(H + 9) * H + j];
            p[11] = 0.f;
        }
        float b2v = be2[0];
        __syncthreads();

        float f[8][9], acc[8], emv[8];
        #pragma unroll
        for (int q = 0; q < 8; q++) {
            int e = w * 512 + q * 64 + lane;
            long idx = (long)b * E + e;
            int2 ev = ((const int2*)edges)[idx];
            int s0 = min(max(ev.x, 0), N - 1);
            int d0 = min(max(ev.y, 0), N - 1);
            const float* cs0 = sC + s0 * 9;
            const float* cd0 = sC + d0 * 9;
            #pragma unroll
            for (int k = 0; k < 8; k++) f[q][k] = cd0[k] - cs0[k];
            f[q][8] = es[idx];
            emv[q] = mask_val(emask, idx, flag);
            acc[q] = b2v;
        }

        #pragma unroll 2
        for (int j = 0; j < H; j++) {
            const float* pj = pack + j * 12;
            float4 wa = *(const float4*)(pj);
            float4 wb = *(const float4*)(pj + 4);
            float4 wc = *(const float4*)(pj + 8);
            #pragma unroll
            for (int q = 0; q < 8; q++) {
                float zA = fmaf(f[q][0], wa.x, wc.z);   // base (+w9 fold)
                zA = fmaf(f[q][1], wa.y, zA);
                zA = fmaf(f[q][2], wa.z, zA);
                zA = fmaf(f[q][3], wa.w, zA);
                float zB = f[q][4] * wb.x;
                zB = fmaf(f[q][5], wb.y, zB);
                zB = fmaf(f[q][6], wb.z, zB);
                zB = fmaf(f[q][7], wb.w, zB);
                zB = fmaf(f[q][8], wc.x, zB);
                acc[q] = fmaf(fmaxf(zA + zB, 0.f), wc.y, acc[q]);
            }
        }

        #pragma unroll
        for (int q = 0; q < 8; q++) {
            long idx = (long)b * E + w * 512 + q * 64 + lane;
            out2[idx] = (emv[q] != 0.f) ? (f[q][8] + g * 0.1f * acc[q]) : 0.f;
        }
    }
}

// ---------------------------------------------------------------------------
// k_fin: edge mean/var -> evar, then out4 = clip(riskbase + 0.2*evar, 0, 1).
// ---------------------------------------------------------------------------
__global__ __launch_bounds__(256) void k_fin(
    const void* __restrict__ emask, const int* __restrict__ flagp,
    const float* __restrict__ out2, const float* __restrict__ riskbase,
    float* __restrict__ out4)
{
    __shared__ float red[256];
    int t = threadIdx.x;
    int b = blockIdx.x;
    int flag = *flagp;

    float x[4], em[4];
    float S1 = 0.f, ce = 0.f;
    #pragma unroll
    for (int q = 0; q < 4; q++) {
        long idx = (long)b * E + t + 256 * q;
        x[q] = out2[idx];
        em[q] = mask_val(emask, idx, flag);
        S1 += x[q]; ce += em[q];
    }
    float S1t = block_sum(S1, red);
    float cet = block_sum(ce, red);
    float mean = S1t / fmaxf(cet, 1.f);
    float v = 0.f;
    #pragma unroll
    for (int q = 0; q < 4; q++) {
        float dd = x[q] - mean;
        v = fmaf(em[q] * dd, dd, v);
    }
    float vt = block_sum(v, red);
    if (t == 0) {
        float var = vt / fmaxf(cet, 1.f);
        float ev = (cet > 1.f) ? var : 0.f;
        float r = riskbase[b] + 0.2f * ev;
        out4[b] = fminf(fmaxf(r, 0.f), 1.f);
    }
}

// ---------------------------------------------------------------------------
extern "C" void kernel_launch(void* const* d_in, const int* in_sizes, int n_in,
                              void* d_out, int out_size, void* d_ws, size_t ws_size,
                              hipStream_t stream) {
    const float* feat   = (const float*)d_in[0];
    const float* cs     = (const float*)d_in[1];
    const float* marg   = (const float*)d_in[2];
    const float* brisk  = (const float*)d_in[3];
    const float* es     = (const float*)d_in[4];
    const float* coords = (const float*)d_in[5];
    const float* unc    = (const float*)d_in[6];
    const float* Wc1    = (const float*)d_in[7];
    const float* bc1    = (const float*)d_in[8];
    const float* Wc2    = (const float*)d_in[9];
    const float* bc2    = (const float*)d_in[10];
    const float* Wn1    = (const float*)d_in[11];
    const float* bn1    = (const float*)d_in[12];
    const float* Wn2    = (const float*)d_in[13];
    const float* bn2    = (const float*)d_in[14];
    const float* We1    = (const float*)d_in[15];
    const float* be1    = (const float*)d_in[16];
    const float* We2    = (const float*)d_in[17];
    const float* be2    = (const float*)d_in[18];
    const float* Wg     = (const float*)d_in[19];
    const float* bg     = (const float*)d_in[20];
    const void*  amask  = d_in[21];
    const void*  emask  = d_in[22];
    const int*   actions= (const int*)d_in[23];
    const int*   edges  = (const int*)d_in[24];

    float* out0 = (float*)d_out;           // refined_scores (B,N)
    float* out1 = out0 + (long)B * N;      // refined_margin (B,)
    float* out2 = out1 + B;                // refined_edge (B,E)
    float* out3 = out2 + (long)B * E;      // top_idx (B,) as float
    float* out4 = out3 + B;                // refined_risk (B,)
    float* out5 = out4 + B;                // refine_gate (B,)

    float* base_n   = (float*)d_ws;                  // B*H
    float* base_e   = base_n + (long)B * H;          // B*H
    float* riskbase = base_e + (long)B * H;          // B
    int*   flag     = (int*)(riskbase + B);

    k_h<<<B / 2, 512, 0, stream>>>(feat, Wc1, bc1, Wc2, bc2, Wn1, bn1, We1, be1,
                                   Wg, bg, marg, brisk,
                                   (const unsigned int*)amask,
                                   base_n, base_e, out5, flag);
    k_ne<<<256 + B, 128, 0, stream>>>(cs, coords, unc, actions, amask,
                                      Wn1, Wn2, bn2, base_n,
                                      es, edges, emask,
                                      We1, We2, be2, base_e,
                                      out5, flag,
                                      out0, out1, out2, out3, riskbase);
    k_fin<<<B, 256, 0, stream>>>(emask, flag, out2, riskbase, out4);
}